// Round 1
// baseline (832.649 us; speedup 1.0000x reference)
//
#include <hip/hip_runtime.h>
#include <hip/hip_bf16.h>

#define NNODES 100000
#define NEDGES 1600000
#define IND 128
#define HD 64
#define OUTD 2
#define NG 64
#define SCAN_CHUNK 1024

// ---------------- degree histogram ----------------
__global__ __launch_bounds__(256) void hist_kernel(const int* __restrict__ dst,
                                                   int* __restrict__ hist, int E) {
    int i = blockIdx.x * 256 + threadIdx.x;
    if (i < E) atomicAdd(&hist[dst[i]], 1);
}

// ---------------- dinv = 1/sqrt(deg) (deg includes self loop) ----------------
__global__ __launch_bounds__(256) void dinv_kernel(const int* __restrict__ hist,
                                                   float* __restrict__ dinv, int n) {
    int i = blockIdx.x * 256 + threadIdx.x;
    if (i < n) {
        float d = (float)(hist[i] + 1);   // +1 self loop
        dinv[i] = 1.0f / sqrtf(d);
    }
}

// ---------------- scan phase A: per-chunk sums ----------------
__global__ __launch_bounds__(256) void scan_sum_kernel(const int* __restrict__ hist,
                                                       int* __restrict__ bsum, int n) {
    __shared__ int wsums[4];
    int lane = threadIdx.x & 63, wv = threadIdx.x >> 6;
    int i0 = blockIdx.x * SCAN_CHUNK + threadIdx.x * 4;
    int t = 0;
#pragma unroll
    for (int k = 0; k < 4; k++) { int i = i0 + k; if (i < n) t += hist[i]; }
#pragma unroll
    for (int d = 32; d > 0; d >>= 1) t += __shfl_down(t, d, 64);
    if (lane == 0) wsums[wv] = t;
    __syncthreads();
    if (threadIdx.x == 0) bsum[blockIdx.x] = wsums[0] + wsums[1] + wsums[2] + wsums[3];
}

// ---------------- scan phase B: exclusive scan of chunk sums (1 wave) -------
__global__ __launch_bounds__(64) void scan_bsums_kernel(int* __restrict__ bsum, int nchunks) {
    int lane = threadIdx.x;
    int cpl = (nchunks + 63) / 64;     // <= 8 assumed
    int vals[8];
    int i0 = lane * cpl;
    int t = 0;
    for (int k = 0; k < cpl; k++) {
        int i = i0 + k;
        vals[k] = (i < nchunks) ? bsum[i] : 0;
        t += vals[k];
    }
    int sc = t;
#pragma unroll
    for (int d = 1; d < 64; d <<= 1) { int v = __shfl_up(sc, d, 64); if (lane >= d) sc += v; }
    int ex = sc - t;
    for (int k = 0; k < cpl; k++) {
        int i = i0 + k;
        if (i < nchunks) bsum[i] = ex;
        ex += vals[k];
    }
}

// ---------------- scan phase C: write exclusive row_ptr ----------------
__global__ __launch_bounds__(256) void scan_write_kernel(const int* __restrict__ hist,
                                                         const int* __restrict__ bofs,
                                                         int* __restrict__ rowptr,
                                                         int n, int total) {
    __shared__ int wsum[4];
    int lane = threadIdx.x & 63, wv = threadIdx.x >> 6;
    int i0 = blockIdx.x * SCAN_CHUNK + threadIdx.x * 4;
    int h[4]; int t = 0;
#pragma unroll
    for (int k = 0; k < 4; k++) { int i = i0 + k; h[k] = (i < n) ? hist[i] : 0; t += h[k]; }
    int sc = t;
#pragma unroll
    for (int d = 1; d < 64; d <<= 1) { int v = __shfl_up(sc, d, 64); if (lane >= d) sc += v; }
    if (lane == 63) wsum[wv] = sc;
    __syncthreads();
    int wofs = 0;
    for (int w = 0; w < wv; w++) wofs += wsum[w];
    int ex = (sc - t) + wofs + bofs[blockIdx.x];
#pragma unroll
    for (int k = 0; k < 4; k++) { int i = i0 + k; if (i < n) rowptr[i] = ex; ex += h[k]; }
    if (blockIdx.x == 0 && threadIdx.x == 0) rowptr[n] = total;
}

// ---------------- CSR scatter: sort edges by dst ----------------
__global__ __launch_bounds__(256) void scatter_kernel(const int* __restrict__ src,
                                                      const int* __restrict__ dst,
                                                      const float* __restrict__ dinv,
                                                      const int* __restrict__ rowptr,
                                                      int* __restrict__ cnt,
                                                      int* __restrict__ ssrc,
                                                      float* __restrict__ swt, int E) {
    int e = blockIdx.x * 256 + threadIdx.x;
    if (e >= E) return;
    int d = dst[e], s = src[e];
    int pos = rowptr[d] + atomicAdd(&cnt[d], 1);
    ssrc[pos] = s;
    swt[pos] = dinv[s] * dinv[d];
}

// ---------------- dense matmul: T[n, 0..63] = X[n, :K] @ W[K, 64] ----------
// wave = 64 nodes (lane = node); thread holds all 64 output features.
// W reads are wave-uniform -> scalar loads through K$.
template <int K>
__global__ __launch_bounds__(256) void mm_kernel(const float* __restrict__ X,
                                                 const float* __restrict__ W,
                                                 float* __restrict__ T, int nn) {
    int gwave = (blockIdx.x * 256 + threadIdx.x) >> 6;
    int lane  = threadIdx.x & 63;
    int n = gwave * 64 + lane;
    bool act = n < nn;
    const float* xr = X + (size_t)n * K;
    float acc[64];
#pragma unroll
    for (int j = 0; j < 64; j++) acc[j] = 0.f;
#pragma unroll 2
    for (int k = 0; k < K; k += 4) {
        float4 xv = act ? *(const float4*)(xr + k) : make_float4(0.f, 0.f, 0.f, 0.f);
#pragma unroll
        for (int kk = 0; kk < 4; kk++) {
            float xs = (&xv.x)[kk];
            const float* wr = W + (size_t)(k + kk) * 64;
#pragma unroll
            for (int j = 0; j < 64; j++) acc[j] += xs * wr[j];
        }
    }
    if (act) {
        float4* o = (float4*)(T + (size_t)n * 64);
#pragma unroll
        for (int j = 0; j < 64; j += 4)
            o[j >> 2] = make_float4(acc[j], acc[j + 1], acc[j + 2], acc[j + 3]);
    }
}

// ---------------- pull aggregation + self loop + bias + relu ----------------
// wave per node, lane = feature.
__global__ __launch_bounds__(256) void agg_kernel(const float* __restrict__ T,
                                                  const int* __restrict__ rowptr,
                                                  const int* __restrict__ ssrc,
                                                  const float* __restrict__ swt,
                                                  const float* __restrict__ dinv,
                                                  const float* __restrict__ bias,
                                                  float* __restrict__ O, int nn) {
    int wave = (blockIdx.x * 256 + threadIdx.x) >> 6;
    int lane = threadIdx.x & 63;
    if (wave >= nn) return;
    int n = wave;
    float di = dinv[n];
    float acc = di * di * T[(size_t)n * 64 + lane];
    int rb = rowptr[n], re = rowptr[n + 1];
    int i = rb;
    for (; i + 1 < re; i += 2) {
        int s0 = ssrc[i], s1 = ssrc[i + 1];
        float w0 = swt[i], w1 = swt[i + 1];
        float v0 = T[(size_t)s0 * 64 + lane];
        float v1 = T[(size_t)s1 * 64 + lane];
        acc += w0 * v0;
        acc += w1 * v1;
    }
    if (i < re) {
        int s0 = ssrc[i];
        acc += swt[i] * T[(size_t)s0 * 64 + lane];
    }
    float v = acc + bias[lane];
    O[(size_t)n * 64 + lane] = v > 0.f ? v : 0.f;
}

// ---------------- mean pool: exploit sorted batch ids ----------------
__global__ __launch_bounds__(256) void pool_kernel(const float* __restrict__ H,
                                                   const int* __restrict__ batch,
                                                   float* __restrict__ pooled,
                                                   float* __restrict__ gcnt, int nn) {
    int wid = (blockIdx.x * 256 + threadIdx.x) >> 6;
    int lane = threadIdx.x & 63;
    int nwaves = (gridDim.x * 256) >> 6;
    int per = (nn + nwaves - 1) / nwaves;
    int n0 = wid * per;
    int n1 = n0 + per; if (n1 > nn) n1 = nn;
    if (n0 >= n1) return;
    int cur = batch[n0];
    float acc = 0.f, cnt = 0.f;
    for (int n = n0; n < n1; ++n) {
        int g = batch[n];
        if (g != cur) {
            atomicAdd(&pooled[cur * 64 + lane], acc);
            if (lane == 0) atomicAdd(&gcnt[cur], cnt);
            acc = 0.f; cnt = 0.f; cur = g;
        }
        acc += H[(size_t)n * 64 + lane];
        cnt += 1.f;
    }
    atomicAdd(&pooled[cur * 64 + lane], acc);
    if (lane == 0) atomicAdd(&gcnt[cur], cnt);
}

// ---------------- MLP head (single block) ----------------
__global__ __launch_bounds__(256) void head_kernel(const float* __restrict__ pooled,
                                                   const float* __restrict__ gcnt,
                                                   const float* __restrict__ Wm1,
                                                   const float* __restrict__ bm1,
                                                   const float* __restrict__ Wm2,
                                                   const float* __restrict__ bm2,
                                                   float* __restrict__ out) {
    __shared__ float P[NG * 64];
    __shared__ float Z[NG * 64];
    int tid = threadIdx.x;
    for (int i = tid; i < NG * 64; i += 256) {
        int g = i >> 6;
        float c = gcnt[g];
        c = c > 1.f ? c : 1.f;
        P[i] = pooled[i] / c;
    }
    __syncthreads();
    for (int i = tid; i < NG * 64; i += 256) {
        int g = i >> 6, j = i & 63;
        float a = bm1[j];
#pragma unroll 8
        for (int k = 0; k < 64; ++k) a += P[g * 64 + k] * Wm1[k * 64 + j];
        Z[i] = a > 0.f ? a : 0.f;
    }
    __syncthreads();
    for (int i = tid; i < NG * OUTD; i += 256) {
        int g = i / OUTD, o = i % OUTD;
        float a = bm2[o];
#pragma unroll 8
        for (int k = 0; k < 64; ++k) a += Z[g * 64 + k] * Wm2[k * OUTD + o];
        out[i] = a;
    }
}

extern "C" void kernel_launch(void* const* d_in, const int* in_sizes, int n_in,
                              void* d_out, int out_size, void* d_ws, size_t ws_size,
                              hipStream_t stream) {
    const float* x    = (const float*)d_in[0];
    const int*  edge  = (const int*)d_in[1];
    const int*  batch = (const int*)d_in[2];
    const float* W1 = (const float*)d_in[3];
    const float* b1 = (const float*)d_in[4];
    const float* W2 = (const float*)d_in[5];
    const float* b2 = (const float*)d_in[6];
    const float* W3 = (const float*)d_in[7];
    const float* b3 = (const float*)d_in[8];
    const float* Wm1 = (const float*)d_in[9];
    const float* bm1 = (const float*)d_in[10];
    const float* Wm2 = (const float*)d_in[11];
    const float* bm2 = (const float*)d_in[12];

    const int N_ = in_sizes[2];           // 100000 (batch length)
    const int E_ = in_sizes[1] / 2;       // 1600000
    const int* src = edge;
    const int* dst = edge + E_;

    // workspace carve (256 B aligned)
    char* w = (char*)d_ws;
    auto alloc = [&](size_t bytes) -> void* {
        void* p = (void*)w;
        w += (bytes + 255) & ~(size_t)255;
        return p;
    };
    float* dinv   = (float*)alloc((size_t)N_ * 4);
    int*   hist   = (int*)alloc((size_t)N_ * 4);
    int*   rowptr = (int*)alloc((size_t)(N_ + 1) * 4);
    int*   cnt    = (int*)alloc((size_t)N_ * 4);
    int*   bsum   = (int*)alloc(512 * 4);
    int*   ssrc   = (int*)alloc((size_t)E_ * 4);
    float* swt    = (float*)alloc((size_t)E_ * 4);
    float* tA     = (float*)alloc((size_t)N_ * 64 * 4);
    float* hB     = (float*)alloc((size_t)N_ * 64 * 4);
    float* pooled = (float*)alloc((size_t)(NG * 64 + NG) * 4);
    float* gcnt   = pooled + NG * 64;

    const int nchunks = (N_ + SCAN_CHUNK - 1) / SCAN_CHUNK;
    const int eblk = (E_ + 255) / 256;
    const int nblk = (N_ + 255) / 256;

    hipMemsetAsync(hist, 0, (size_t)N_ * 4, stream);
    hipMemsetAsync(cnt, 0, (size_t)N_ * 4, stream);
    hipMemsetAsync(pooled, 0, (size_t)(NG * 64 + NG) * 4, stream);

    hist_kernel<<<eblk, 256, 0, stream>>>(dst, hist, E_);
    dinv_kernel<<<nblk, 256, 0, stream>>>(hist, dinv, N_);
    scan_sum_kernel<<<nchunks, 256, 0, stream>>>(hist, bsum, N_);
    scan_bsums_kernel<<<1, 64, 0, stream>>>(bsum, nchunks);
    scan_write_kernel<<<nchunks, 256, 0, stream>>>(hist, bsum, rowptr, N_, E_);
    scatter_kernel<<<eblk, 256, 0, stream>>>(src, dst, dinv, rowptr, cnt, ssrc, swt, E_);

    const int mmblk = (N_ + 255) / 256;           // 256 nodes per block
    const int aggblk = (N_ + 3) / 4;              // 4 waves (nodes) per block

    // layer 1: t = x @ W1 ; h = agg(t) + b1, relu
    mm_kernel<IND><<<mmblk, 256, 0, stream>>>(x, W1, tA, N_);
    agg_kernel<<<aggblk, 256, 0, stream>>>(tA, rowptr, ssrc, swt, dinv, b1, hB, N_);
    // layer 2
    mm_kernel<HD><<<mmblk, 256, 0, stream>>>(hB, W2, tA, N_);
    agg_kernel<<<aggblk, 256, 0, stream>>>(tA, rowptr, ssrc, swt, dinv, b2, hB, N_);
    // layer 3
    mm_kernel<HD><<<mmblk, 256, 0, stream>>>(hB, W3, tA, N_);
    agg_kernel<<<aggblk, 256, 0, stream>>>(tA, rowptr, ssrc, swt, dinv, b3, hB, N_);

    // pool + head
    pool_kernel<<<256, 256, 0, stream>>>(hB, batch, pooled, gcnt, N_);
    head_kernel<<<1, 256, 0, stream>>>(pooled, gcnt, Wm1, bm1, Wm2, bm2, (float*)d_out);
}

// Round 2
// 802.318 us; speedup vs baseline: 1.0378x; 1.0378x over previous
//
#include <hip/hip_runtime.h>
#include <hip/hip_bf16.h>

#define NNODES 100000
#define NEDGES 1600000
#define IND 128
#define HD 64
#define OUTD 2
#define NG 64
#define SCAN_CHUNK 1024

// ---------------- degree histogram ----------------
__global__ __launch_bounds__(256) void hist_kernel(const int* __restrict__ dst,
                                                   int* __restrict__ hist, int E) {
    int i = blockIdx.x * 256 + threadIdx.x;
    if (i < E) atomicAdd(&hist[dst[i]], 1);
}

// ---------------- dinv = 1/sqrt(deg) (deg includes self loop) ----------------
__global__ __launch_bounds__(256) void dinv_kernel(const int* __restrict__ hist,
                                                   float* __restrict__ dinv, int n) {
    int i = blockIdx.x * 256 + threadIdx.x;
    if (i < n) {
        float d = (float)(hist[i] + 1);   // +1 self loop
        dinv[i] = 1.0f / sqrtf(d);
    }
}

// ---------------- scan phase A: per-chunk sums ----------------
__global__ __launch_bounds__(256) void scan_sum_kernel(const int* __restrict__ hist,
                                                       int* __restrict__ bsum, int n) {
    __shared__ int wsums[4];
    int lane = threadIdx.x & 63, wv = threadIdx.x >> 6;
    int i0 = blockIdx.x * SCAN_CHUNK + threadIdx.x * 4;
    int t = 0;
#pragma unroll
    for (int k = 0; k < 4; k++) { int i = i0 + k; if (i < n) t += hist[i]; }
#pragma unroll
    for (int d = 32; d > 0; d >>= 1) t += __shfl_down(t, d, 64);
    if (lane == 0) wsums[wv] = t;
    __syncthreads();
    if (threadIdx.x == 0) bsum[blockIdx.x] = wsums[0] + wsums[1] + wsums[2] + wsums[3];
}

// ---------------- scan phase B: exclusive scan of chunk sums (1 wave) -------
__global__ __launch_bounds__(64) void scan_bsums_kernel(int* __restrict__ bsum, int nchunks) {
    int lane = threadIdx.x;
    int cpl = (nchunks + 63) / 64;     // <= 8 assumed
    int vals[8];
    int i0 = lane * cpl;
    int t = 0;
    for (int k = 0; k < cpl; k++) {
        int i = i0 + k;
        vals[k] = (i < nchunks) ? bsum[i] : 0;
        t += vals[k];
    }
    int sc = t;
#pragma unroll
    for (int d = 1; d < 64; d <<= 1) { int v = __shfl_up(sc, d, 64); if (lane >= d) sc += v; }
    int ex = sc - t;
    for (int k = 0; k < cpl; k++) {
        int i = i0 + k;
        if (i < nchunks) bsum[i] = ex;
        ex += vals[k];
    }
}

// ---------------- scan phase C: write exclusive row_ptr ----------------
__global__ __launch_bounds__(256) void scan_write_kernel(const int* __restrict__ hist,
                                                         const int* __restrict__ bofs,
                                                         int* __restrict__ rowptr,
                                                         int n, int total) {
    __shared__ int wsum[4];
    int lane = threadIdx.x & 63, wv = threadIdx.x >> 6;
    int i0 = blockIdx.x * SCAN_CHUNK + threadIdx.x * 4;
    int h[4]; int t = 0;
#pragma unroll
    for (int k = 0; k < 4; k++) { int i = i0 + k; h[k] = (i < n) ? hist[i] : 0; t += h[k]; }
    int sc = t;
#pragma unroll
    for (int d = 1; d < 64; d <<= 1) { int v = __shfl_up(sc, d, 64); if (lane >= d) sc += v; }
    if (lane == 63) wsum[wv] = sc;
    __syncthreads();
    int wofs = 0;
    for (int w = 0; w < wv; w++) wofs += wsum[w];
    int ex = (sc - t) + wofs + bofs[blockIdx.x];
#pragma unroll
    for (int k = 0; k < 4; k++) { int i = i0 + k; if (i < n) rowptr[i] = ex; ex += h[k]; }
    if (blockIdx.x == 0 && threadIdx.x == 0) rowptr[n] = total;
}

// ---------------- CSR scatter: sort edges by dst (ssrc only) ----------------
// hist is consumed as a countdown counter -> no cnt array, no extra memset.
__global__ __launch_bounds__(256) void scatter_kernel(const int* __restrict__ src,
                                                      const int* __restrict__ dst,
                                                      const int* __restrict__ rowptr,
                                                      int* __restrict__ hist,
                                                      int* __restrict__ ssrc, int E) {
    int e = blockIdx.x * 256 + threadIdx.x;
    if (e >= E) return;
    int d = dst[e];
    int pos = rowptr[d] + atomicSub(&hist[d], 1) - 1;
    ssrc[pos] = src[e];
}

// ---------------- dense matmul: T[n, 0..63] = X[n, :K] @ W[K, 64] ----------
// lane = output feature j; wave = 8 consecutive nodes.
// W staged in LDS (per-lane coalesced, 2-way bank alias = free).
// x[n][k] is wave-uniform -> scalar s_load_dwordx4 via readfirstlane'd base.
// Inner loop: pure v_fmac_f32 v, s, v at VALU peak.
template <int K>
__global__ __launch_bounds__(256) void mm_kernel(const float* __restrict__ X,
                                                 const float* __restrict__ W,
                                                 float* __restrict__ T, int nn) {
    __shared__ float Ws[K * 64];
    for (int i = threadIdx.x; i < K * 16; i += 256)
        ((float4*)Ws)[i] = ((const float4*)W)[i];
    __syncthreads();
    int lane = threadIdx.x & 63;
    int wv = __builtin_amdgcn_readfirstlane(threadIdx.x >> 6);
    int nbase = blockIdx.x * 32 + wv * 8;
    if (nbase >= nn) return;
    const float* xr = X + (size_t)nbase * K;   // wave-uniform pointer
    float acc[8];
#pragma unroll
    for (int u = 0; u < 8; u++) acc[u] = 0.f;

    if (nbase + 8 <= nn) {
#pragma unroll 2
        for (int k = 0; k < K; k += 4) {
            float w0 = Ws[(k + 0) * 64 + lane];
            float w1 = Ws[(k + 1) * 64 + lane];
            float w2 = Ws[(k + 2) * 64 + lane];
            float w3 = Ws[(k + 3) * 64 + lane];
#pragma unroll
            for (int u = 0; u < 8; u++) {
                float4 xv = *(const float4*)(xr + u * K + k);  // s_load_dwordx4
                acc[u] += xv.x * w0;
                acc[u] += xv.y * w1;
                acc[u] += xv.z * w2;
                acc[u] += xv.w * w3;
            }
        }
#pragma unroll
        for (int u = 0; u < 8; u++)
            T[(size_t)(nbase + u) * 64 + lane] = acc[u];
    } else {
        int nrem = nn - nbase;
        for (int u = 0; u < nrem; u++) {
            float a = 0.f;
            for (int k = 0; k < K; k += 4) {
                float4 xv = *(const float4*)(xr + u * K + k);
                a += xv.x * Ws[(k + 0) * 64 + lane];
                a += xv.y * Ws[(k + 1) * 64 + lane];
                a += xv.z * Ws[(k + 2) * 64 + lane];
                a += xv.w * Ws[(k + 3) * 64 + lane];
            }
            T[(size_t)(nbase + u) * 64 + lane] = a;
        }
    }
}

// ---------------- pull aggregation + self loop + bias + relu ----------------
// wave per node (readfirstlane -> rowptr/ssrc/dinv become s_loads), lane = feature.
__global__ __launch_bounds__(256) void agg_kernel(const float* __restrict__ T,
                                                  const int* __restrict__ rowptr,
                                                  const int* __restrict__ ssrc,
                                                  const float* __restrict__ dinv,
                                                  const float* __restrict__ bias,
                                                  float* __restrict__ O, int nn) {
    int wave = __builtin_amdgcn_readfirstlane((blockIdx.x * 256 + threadIdx.x) >> 6);
    int lane = threadIdx.x & 63;
    if (wave >= nn) return;
    int n = wave;
    float di = dinv[n];
    float acc = di * di * T[(size_t)n * 64 + lane];
    int rb = rowptr[n], re = rowptr[n + 1];
    int i = rb;
    for (; i + 3 < re; i += 4) {
        int s0 = ssrc[i], s1 = ssrc[i + 1], s2 = ssrc[i + 2], s3 = ssrc[i + 3];
        float w0 = di * dinv[s0];
        float w1 = di * dinv[s1];
        float w2 = di * dinv[s2];
        float w3 = di * dinv[s3];
        float v0 = T[(size_t)s0 * 64 + lane];
        float v1 = T[(size_t)s1 * 64 + lane];
        float v2 = T[(size_t)s2 * 64 + lane];
        float v3 = T[(size_t)s3 * 64 + lane];
        acc += w0 * v0;
        acc += w1 * v1;
        acc += w2 * v2;
        acc += w3 * v3;
    }
    for (; i < re; i++) {
        int s0 = ssrc[i];
        acc += di * dinv[s0] * T[(size_t)s0 * 64 + lane];
    }
    float v = acc + bias[lane];
    O[(size_t)n * 64 + lane] = v > 0.f ? v : 0.f;
}

// ---------------- mean pool: exploit sorted batch ids ----------------
__global__ __launch_bounds__(256) void pool_kernel(const float* __restrict__ H,
                                                   const int* __restrict__ batch,
                                                   float* __restrict__ pooled,
                                                   float* __restrict__ gcnt, int nn) {
    int wid = (blockIdx.x * 256 + threadIdx.x) >> 6;
    int lane = threadIdx.x & 63;
    int nwaves = (gridDim.x * 256) >> 6;
    int per = (nn + nwaves - 1) / nwaves;
    int n0 = wid * per;
    int n1 = n0 + per; if (n1 > nn) n1 = nn;
    if (n0 >= n1) return;
    int cur = batch[n0];
    float acc = 0.f, cnt = 0.f;
    for (int n = n0; n < n1; ++n) {
        int g = batch[n];
        if (g != cur) {
            atomicAdd(&pooled[cur * 64 + lane], acc);
            if (lane == 0) atomicAdd(&gcnt[cur], cnt);
            acc = 0.f; cnt = 0.f; cur = g;
        }
        acc += H[(size_t)n * 64 + lane];
        cnt += 1.f;
    }
    atomicAdd(&pooled[cur * 64 + lane], acc);
    if (lane == 0) atomicAdd(&gcnt[cur], cnt);
}

// ---------------- MLP head (single block) ----------------
__global__ __launch_bounds__(256) void head_kernel(const float* __restrict__ pooled,
                                                   const float* __restrict__ gcnt,
                                                   const float* __restrict__ Wm1,
                                                   const float* __restrict__ bm1,
                                                   const float* __restrict__ Wm2,
                                                   const float* __restrict__ bm2,
                                                   float* __restrict__ out) {
    __shared__ float P[NG * 64];
    __shared__ float Z[NG * 64];
    int tid = threadIdx.x;
    for (int i = tid; i < NG * 64; i += 256) {
        int g = i >> 6;
        float c = gcnt[g];
        c = c > 1.f ? c : 1.f;
        P[i] = pooled[i] / c;
    }
    __syncthreads();
    for (int i = tid; i < NG * 64; i += 256) {
        int g = i >> 6, j = i & 63;
        float a = bm1[j];
#pragma unroll 8
        for (int k = 0; k < 64; ++k) a += P[g * 64 + k] * Wm1[k * 64 + j];
        Z[i] = a > 0.f ? a : 0.f;
    }
    __syncthreads();
    for (int i = tid; i < NG * OUTD; i += 256) {
        int g = i / OUTD, o = i % OUTD;
        float a = bm2[o];
#pragma unroll 8
        for (int k = 0; k < 64; ++k) a += Z[g * 64 + k] * Wm2[k * OUTD + o];
        out[i] = a;
    }
}

extern "C" void kernel_launch(void* const* d_in, const int* in_sizes, int n_in,
                              void* d_out, int out_size, void* d_ws, size_t ws_size,
                              hipStream_t stream) {
    const float* x    = (const float*)d_in[0];
    const int*  edge  = (const int*)d_in[1];
    const int*  batch = (const int*)d_in[2];
    const float* W1 = (const float*)d_in[3];
    const float* b1 = (const float*)d_in[4];
    const float* W2 = (const float*)d_in[5];
    const float* b2 = (const float*)d_in[6];
    const float* W3 = (const float*)d_in[7];
    const float* b3 = (const float*)d_in[8];
    const float* Wm1 = (const float*)d_in[9];
    const float* bm1 = (const float*)d_in[10];
    const float* Wm2 = (const float*)d_in[11];
    const float* bm2 = (const float*)d_in[12];

    const int N_ = in_sizes[2];           // 100000 (batch length)
    const int E_ = in_sizes[1] / 2;       // 1600000
    const int* src = edge;
    const int* dst = edge + E_;

    // workspace carve (256 B aligned)
    char* w = (char*)d_ws;
    auto alloc = [&](size_t bytes) -> void* {
        void* p = (void*)w;
        w += (bytes + 255) & ~(size_t)255;
        return p;
    };
    float* dinv   = (float*)alloc((size_t)N_ * 4);
    int*   hist   = (int*)alloc((size_t)N_ * 4);
    int*   rowptr = (int*)alloc((size_t)(N_ + 1) * 4);
    int*   bsum   = (int*)alloc(512 * 4);
    int*   ssrc   = (int*)alloc((size_t)E_ * 4);
    float* tA     = (float*)alloc((size_t)N_ * 64 * 4);
    float* hB     = (float*)alloc((size_t)N_ * 64 * 4);
    float* pooled = (float*)alloc((size_t)(NG * 64 + NG) * 4);
    float* gcnt   = pooled + NG * 64;

    const int nchunks = (N_ + SCAN_CHUNK - 1) / SCAN_CHUNK;
    const int eblk = (E_ + 255) / 256;
    const int nblk = (N_ + 255) / 256;

    hipMemsetAsync(hist, 0, (size_t)N_ * 4, stream);
    hipMemsetAsync(pooled, 0, (size_t)(NG * 64 + NG) * 4, stream);

    hist_kernel<<<eblk, 256, 0, stream>>>(dst, hist, E_);
    dinv_kernel<<<nblk, 256, 0, stream>>>(hist, dinv, N_);
    scan_sum_kernel<<<nchunks, 256, 0, stream>>>(hist, bsum, N_);
    scan_bsums_kernel<<<1, 64, 0, stream>>>(bsum, nchunks);
    scan_write_kernel<<<nchunks, 256, 0, stream>>>(hist, bsum, rowptr, N_, E_);
    scatter_kernel<<<eblk, 256, 0, stream>>>(src, dst, rowptr, hist, ssrc, E_);

    const int mmblk = (N_ + 31) / 32;             // 32 nodes per block (8/wave)
    const int aggblk = (N_ + 3) / 4;              // 4 waves (nodes) per block

    // layer 1: t = x @ W1 ; h = agg(t) + b1, relu
    mm_kernel<IND><<<mmblk, 256, 0, stream>>>(x, W1, tA, N_);
    agg_kernel<<<aggblk, 256, 0, stream>>>(tA, rowptr, ssrc, dinv, b1, hB, N_);
    // layer 2
    mm_kernel<HD><<<mmblk, 256, 0, stream>>>(hB, W2, tA, N_);
    agg_kernel<<<aggblk, 256, 0, stream>>>(tA, rowptr, ssrc, dinv, b2, hB, N_);
    // layer 3
    mm_kernel<HD><<<mmblk, 256, 0, stream>>>(hB, W3, tA, N_);
    agg_kernel<<<aggblk, 256, 0, stream>>>(tA, rowptr, ssrc, dinv, b3, hB, N_);

    // pool + head
    pool_kernel<<<256, 256, 0, stream>>>(hB, batch, pooled, gcnt, N_);
    head_kernel<<<1, 256, 0, stream>>>(pooled, gcnt, Wm1, bm1, Wm2, bm2, (float*)d_out);
}

// Round 3
// 650.365 us; speedup vs baseline: 1.2803x; 1.2336x over previous
//
#include <hip/hip_runtime.h>
#include <hip/hip_bf16.h>

#define NNODES 100000
#define NEDGES 1600000
#define IND 128
#define HD 64
#define OUTD 2
#define NG 64
#define SCAN_CHUNK 1024

// ---------------- degree histogram ----------------
__global__ __launch_bounds__(256) void hist_kernel(const int* __restrict__ dst,
                                                   int* __restrict__ hist, int E) {
    int i = blockIdx.x * 256 + threadIdx.x;
    if (i < E) atomicAdd(&hist[dst[i]], 1);
}

// ---------------- dinv = 1/sqrt(deg) (deg includes self loop) ----------------
__global__ __launch_bounds__(256) void dinv_kernel(const int* __restrict__ hist,
                                                   float* __restrict__ dinv, int n) {
    int i = blockIdx.x * 256 + threadIdx.x;
    if (i < n) {
        float d = (float)(hist[i] + 1);   // +1 self loop
        dinv[i] = 1.0f / sqrtf(d);
    }
}

// ---------------- scan phase A: per-chunk sums ----------------
__global__ __launch_bounds__(256) void scan_sum_kernel(const int* __restrict__ hist,
                                                       int* __restrict__ bsum, int n) {
    __shared__ int wsums[4];
    int lane = threadIdx.x & 63, wv = threadIdx.x >> 6;
    int i0 = blockIdx.x * SCAN_CHUNK + threadIdx.x * 4;
    int t = 0;
#pragma unroll
    for (int k = 0; k < 4; k++) { int i = i0 + k; if (i < n) t += hist[i]; }
#pragma unroll
    for (int d = 32; d > 0; d >>= 1) t += __shfl_down(t, d, 64);
    if (lane == 0) wsums[wv] = t;
    __syncthreads();
    if (threadIdx.x == 0) bsum[blockIdx.x] = wsums[0] + wsums[1] + wsums[2] + wsums[3];
}

// ---------------- scan phase B: exclusive scan of chunk sums (1 wave) -------
__global__ __launch_bounds__(64) void scan_bsums_kernel(int* __restrict__ bsum, int nchunks) {
    int lane = threadIdx.x;
    int cpl = (nchunks + 63) / 64;     // <= 8 assumed
    int vals[8];
    int i0 = lane * cpl;
    int t = 0;
    for (int k = 0; k < cpl; k++) {
        int i = i0 + k;
        vals[k] = (i < nchunks) ? bsum[i] : 0;
        t += vals[k];
    }
    int sc = t;
#pragma unroll
    for (int d = 1; d < 64; d <<= 1) { int v = __shfl_up(sc, d, 64); if (lane >= d) sc += v; }
    int ex = sc - t;
    for (int k = 0; k < cpl; k++) {
        int i = i0 + k;
        if (i < nchunks) bsum[i] = ex;
        ex += vals[k];
    }
}

// ---------------- scan phase C: write exclusive row_ptr ----------------
__global__ __launch_bounds__(256) void scan_write_kernel(const int* __restrict__ hist,
                                                         const int* __restrict__ bofs,
                                                         int* __restrict__ rowptr,
                                                         int n, int total) {
    __shared__ int wsum[4];
    int lane = threadIdx.x & 63, wv = threadIdx.x >> 6;
    int i0 = blockIdx.x * SCAN_CHUNK + threadIdx.x * 4;
    int h[4]; int t = 0;
#pragma unroll
    for (int k = 0; k < 4; k++) { int i = i0 + k; h[k] = (i < n) ? hist[i] : 0; t += h[k]; }
    int sc = t;
#pragma unroll
    for (int d = 1; d < 64; d <<= 1) { int v = __shfl_up(sc, d, 64); if (lane >= d) sc += v; }
    if (lane == 63) wsum[wv] = sc;
    __syncthreads();
    int wofs = 0;
    for (int w = 0; w < wv; w++) wofs += wsum[w];
    int ex = (sc - t) + wofs + bofs[blockIdx.x];
#pragma unroll
    for (int k = 0; k < 4; k++) { int i = i0 + k; if (i < n) rowptr[i] = ex; ex += h[k]; }
    if (blockIdx.x == 0 && threadIdx.x == 0) rowptr[n] = total;
}

// ---------------- CSR scatter: sort edges by dst (ssrc only) ----------------
// hist is consumed as a countdown counter -> no cnt array, no extra memset.
__global__ __launch_bounds__(256) void scatter_kernel(const int* __restrict__ src,
                                                      const int* __restrict__ dst,
                                                      const int* __restrict__ rowptr,
                                                      int* __restrict__ hist,
                                                      int* __restrict__ ssrc, int E) {
    int e = blockIdx.x * 256 + threadIdx.x;
    if (e >= E) return;
    int d = dst[e];
    int pos = rowptr[d] + atomicSub(&hist[d], 1) - 1;
    ssrc[pos] = src[e];
}

// ---------------- dense matmul: T[n, 0..63] = X[n, :K] @ W[K, 64] ----------
// 256 threads; thread tile = 4 nodes x 8 features. No LDS (LDS would be the
// bottleneck at ~1 B/fma). X loads: float4 per node per 4k, 8 lanes share each
// address (HW dedup). W loads: L1-resident (16-32 KB). Inner loop is a pure
// v_fmac_f32 stream -> VALU-bound.
template <int K>
__global__ __launch_bounds__(256) void mm_kernel(const float* __restrict__ X,
                                                 const float* __restrict__ W,
                                                 float* __restrict__ T, int nn) {
    const int lane   = threadIdx.x & 63;
    const int wv     = threadIdx.x >> 6;
    const int feat_t = lane & 7;          // 8 feature groups of 8
    const int node_t = lane >> 3;         // 8 node groups of 4 -> 32 nodes/wave
    const int j0 = feat_t * 8;
    const int nb = blockIdx.x * 128 + wv * 32 + node_t * 4;
    if (blockIdx.x * 128 >= nn) return;

    // clamp tail rows (loads read duplicate data; stores are guarded)
    const int nclamp = nn - 1;
    const float* xr0 = X + (size_t)min(nb + 0, nclamp) * K;
    const float* xr1 = X + (size_t)min(nb + 1, nclamp) * K;
    const float* xr2 = X + (size_t)min(nb + 2, nclamp) * K;
    const float* xr3 = X + (size_t)min(nb + 3, nclamp) * K;

    float acc[4][8];
#pragma unroll
    for (int u = 0; u < 4; u++)
#pragma unroll
        for (int v = 0; v < 8; v++) acc[u][v] = 0.f;

#pragma unroll 2
    for (int k = 0; k < K; k += 4) {
        float4 x0 = *(const float4*)(xr0 + k);
        float4 x1 = *(const float4*)(xr1 + k);
        float4 x2 = *(const float4*)(xr2 + k);
        float4 x3 = *(const float4*)(xr3 + k);
#pragma unroll
        for (int kk = 0; kk < 4; kk++) {
            float4 wa = *(const float4*)(W + (size_t)(k + kk) * 64 + j0);
            float4 wb = *(const float4*)(W + (size_t)(k + kk) * 64 + j0 + 4);
            float xs0 = (&x0.x)[kk];
            float xs1 = (&x1.x)[kk];
            float xs2 = (&x2.x)[kk];
            float xs3 = (&x3.x)[kk];
            acc[0][0] += xs0 * wa.x; acc[0][1] += xs0 * wa.y;
            acc[0][2] += xs0 * wa.z; acc[0][3] += xs0 * wa.w;
            acc[0][4] += xs0 * wb.x; acc[0][5] += xs0 * wb.y;
            acc[0][6] += xs0 * wb.z; acc[0][7] += xs0 * wb.w;
            acc[1][0] += xs1 * wa.x; acc[1][1] += xs1 * wa.y;
            acc[1][2] += xs1 * wa.z; acc[1][3] += xs1 * wa.w;
            acc[1][4] += xs1 * wb.x; acc[1][5] += xs1 * wb.y;
            acc[1][6] += xs1 * wb.z; acc[1][7] += xs1 * wb.w;
            acc[2][0] += xs2 * wa.x; acc[2][1] += xs2 * wa.y;
            acc[2][2] += xs2 * wa.z; acc[2][3] += xs2 * wa.w;
            acc[2][4] += xs2 * wb.x; acc[2][5] += xs2 * wb.y;
            acc[2][6] += xs2 * wb.z; acc[2][7] += xs2 * wb.w;
            acc[3][0] += xs3 * wa.x; acc[3][1] += xs3 * wa.y;
            acc[3][2] += xs3 * wa.z; acc[3][3] += xs3 * wa.w;
            acc[3][4] += xs3 * wb.x; acc[3][5] += xs3 * wb.y;
            acc[3][6] += xs3 * wb.z; acc[3][7] += xs3 * wb.w;
        }
    }

#pragma unroll
    for (int u = 0; u < 4; u++) {
        if (nb + u < nn) {
            float* o = T + (size_t)(nb + u) * 64 + j0;
            *(float4*)(o)     = make_float4(acc[u][0], acc[u][1], acc[u][2], acc[u][3]);
            *(float4*)(o + 4) = make_float4(acc[u][4], acc[u][5], acc[u][6], acc[u][7]);
        }
    }
}

// ---------------- pull aggregation + self loop + bias + relu ----------------
// wave per node (readfirstlane -> rowptr/ssrc/dinv become s_loads), lane = feature.
__global__ __launch_bounds__(256) void agg_kernel(const float* __restrict__ T,
                                                  const int* __restrict__ rowptr,
                                                  const int* __restrict__ ssrc,
                                                  const float* __restrict__ dinv,
                                                  const float* __restrict__ bias,
                                                  float* __restrict__ O, int nn) {
    int wave = __builtin_amdgcn_readfirstlane((blockIdx.x * 256 + threadIdx.x) >> 6);
    int lane = threadIdx.x & 63;
    if (wave >= nn) return;
    int n = wave;
    float di = dinv[n];
    float acc = di * di * T[(size_t)n * 64 + lane];
    int rb = rowptr[n], re = rowptr[n + 1];
    int i = rb;
    for (; i + 3 < re; i += 4) {
        int s0 = ssrc[i], s1 = ssrc[i + 1], s2 = ssrc[i + 2], s3 = ssrc[i + 3];
        float w0 = di * dinv[s0];
        float w1 = di * dinv[s1];
        float w2 = di * dinv[s2];
        float w3 = di * dinv[s3];
        float v0 = T[(size_t)s0 * 64 + lane];
        float v1 = T[(size_t)s1 * 64 + lane];
        float v2 = T[(size_t)s2 * 64 + lane];
        float v3 = T[(size_t)s3 * 64 + lane];
        acc += w0 * v0;
        acc += w1 * v1;
        acc += w2 * v2;
        acc += w3 * v3;
    }
    for (; i < re; i++) {
        int s0 = ssrc[i];
        acc += di * dinv[s0] * T[(size_t)s0 * 64 + lane];
    }
    float v = acc + bias[lane];
    O[(size_t)n * 64 + lane] = v > 0.f ? v : 0.f;
}

// ---------------- mean pool: exploit sorted batch ids ----------------
__global__ __launch_bounds__(256) void pool_kernel(const float* __restrict__ H,
                                                   const int* __restrict__ batch,
                                                   float* __restrict__ pooled,
                                                   float* __restrict__ gcnt, int nn) {
    int wid = (blockIdx.x * 256 + threadIdx.x) >> 6;
    int lane = threadIdx.x & 63;
    int nwaves = (gridDim.x * 256) >> 6;
    int per = (nn + nwaves - 1) / nwaves;
    int n0 = wid * per;
    int n1 = n0 + per; if (n1 > nn) n1 = nn;
    if (n0 >= n1) return;
    int cur = batch[n0];
    float acc = 0.f, cnt = 0.f;
    for (int n = n0; n < n1; ++n) {
        int g = batch[n];
        if (g != cur) {
            atomicAdd(&pooled[cur * 64 + lane], acc);
            if (lane == 0) atomicAdd(&gcnt[cur], cnt);
            acc = 0.f; cnt = 0.f; cur = g;
        }
        acc += H[(size_t)n * 64 + lane];
        cnt += 1.f;
    }
    atomicAdd(&pooled[cur * 64 + lane], acc);
    if (lane == 0) atomicAdd(&gcnt[cur], cnt);
}

// ---------------- MLP head (single block) ----------------
__global__ __launch_bounds__(256) void head_kernel(const float* __restrict__ pooled,
                                                   const float* __restrict__ gcnt,
                                                   const float* __restrict__ Wm1,
                                                   const float* __restrict__ bm1,
                                                   const float* __restrict__ Wm2,
                                                   const float* __restrict__ bm2,
                                                   float* __restrict__ out) {
    __shared__ float P[NG * 64];
    __shared__ float Z[NG * 64];
    int tid = threadIdx.x;
    for (int i = tid; i < NG * 64; i += 256) {
        int g = i >> 6;
        float c = gcnt[g];
        c = c > 1.f ? c : 1.f;
        P[i] = pooled[i] / c;
    }
    __syncthreads();
    for (int i = tid; i < NG * 64; i += 256) {
        int g = i >> 6, j = i & 63;
        float a = bm1[j];
#pragma unroll 8
        for (int k = 0; k < 64; ++k) a += P[g * 64 + k] * Wm1[k * 64 + j];
        Z[i] = a > 0.f ? a : 0.f;
    }
    __syncthreads();
    for (int i = tid; i < NG * OUTD; i += 256) {
        int g = i / OUTD, o = i % OUTD;
        float a = bm2[o];
#pragma unroll 8
        for (int k = 0; k < 64; ++k) a += Z[g * 64 + k] * Wm2[k * OUTD + o];
        out[i] = a;
    }
}

extern "C" void kernel_launch(void* const* d_in, const int* in_sizes, int n_in,
                              void* d_out, int out_size, void* d_ws, size_t ws_size,
                              hipStream_t stream) {
    const float* x    = (const float*)d_in[0];
    const int*  edge  = (const int*)d_in[1];
    const int*  batch = (const int*)d_in[2];
    const float* W1 = (const float*)d_in[3];
    const float* b1 = (const float*)d_in[4];
    const float* W2 = (const float*)d_in[5];
    const float* b2 = (const float*)d_in[6];
    const float* W3 = (const float*)d_in[7];
    const float* b3 = (const float*)d_in[8];
    const float* Wm1 = (const float*)d_in[9];
    const float* bm1 = (const float*)d_in[10];
    const float* Wm2 = (const float*)d_in[11];
    const float* bm2 = (const float*)d_in[12];

    const int N_ = in_sizes[2];           // 100000 (batch length)
    const int E_ = in_sizes[1] / 2;       // 1600000
    const int* src = edge;
    const int* dst = edge + E_;

    // workspace carve (256 B aligned)
    char* w = (char*)d_ws;
    auto alloc = [&](size_t bytes) -> void* {
        void* p = (void*)w;
        w += (bytes + 255) & ~(size_t)255;
        return p;
    };
    float* dinv   = (float*)alloc((size_t)N_ * 4);
    int*   hist   = (int*)alloc((size_t)N_ * 4);
    int*   rowptr = (int*)alloc((size_t)(N_ + 1) * 4);
    int*   bsum   = (int*)alloc(512 * 4);
    int*   ssrc   = (int*)alloc((size_t)E_ * 4);
    float* tA     = (float*)alloc((size_t)N_ * 64 * 4);
    float* hB     = (float*)alloc((size_t)N_ * 64 * 4);
    float* pooled = (float*)alloc((size_t)(NG * 64 + NG) * 4);
    float* gcnt   = pooled + NG * 64;

    const int nchunks = (N_ + SCAN_CHUNK - 1) / SCAN_CHUNK;
    const int eblk = (E_ + 255) / 256;
    const int nblk = (N_ + 255) / 256;

    hipMemsetAsync(hist, 0, (size_t)N_ * 4, stream);
    hipMemsetAsync(pooled, 0, (size_t)(NG * 64 + NG) * 4, stream);

    hist_kernel<<<eblk, 256, 0, stream>>>(dst, hist, E_);
    dinv_kernel<<<nblk, 256, 0, stream>>>(hist, dinv, N_);
    scan_sum_kernel<<<nchunks, 256, 0, stream>>>(hist, bsum, N_);
    scan_bsums_kernel<<<1, 64, 0, stream>>>(bsum, nchunks);
    scan_write_kernel<<<nchunks, 256, 0, stream>>>(hist, bsum, rowptr, N_, E_);
    scatter_kernel<<<eblk, 256, 0, stream>>>(src, dst, rowptr, hist, ssrc, E_);

    const int mmblk = (N_ + 127) / 128;           // 128 nodes per block
    const int aggblk = (N_ + 3) / 4;              // 4 waves (nodes) per block

    // layer 1: t = x @ W1 ; h = agg(t) + b1, relu
    mm_kernel<IND><<<mmblk, 256, 0, stream>>>(x, W1, tA, N_);
    agg_kernel<<<aggblk, 256, 0, stream>>>(tA, rowptr, ssrc, dinv, b1, hB, N_);
    // layer 2
    mm_kernel<HD><<<mmblk, 256, 0, stream>>>(hB, W2, tA, N_);
    agg_kernel<<<aggblk, 256, 0, stream>>>(tA, rowptr, ssrc, dinv, b2, hB, N_);
    // layer 3
    mm_kernel<HD><<<mmblk, 256, 0, stream>>>(hB, W3, tA, N_);
    agg_kernel<<<aggblk, 256, 0, stream>>>(tA, rowptr, ssrc, dinv, b3, hB, N_);

    // pool + head
    pool_kernel<<<256, 256, 0, stream>>>(hB, batch, pooled, gcnt, N_);
    head_kernel<<<1, 256, 0, stream>>>(pooled, gcnt, Wm1, bm1, Wm2, bm2, (float*)d_out);
}

// Round 4
// 541.695 us; speedup vs baseline: 1.5371x; 1.2006x over previous
//
#include <hip/hip_runtime.h>
#include <hip/hip_bf16.h>

#define NNODES 100000
#define NEDGES 1600000
#define IND 128
#define HD 64
#define OUTD 2
#define NG 64
#define SCAN_CHUNK 1024
#define BINSHIFT 9
#define BINSZ 512            // nodes per bin
#define PB 256               // partition blocks

// ============ binned CSR build ============
// A: per-block bin histogram (LDS), no global atomics.
__global__ __launch_bounds__(256) void binA_kernel(const int* __restrict__ dst,
                                                   int* __restrict__ bbc,
                                                   int E, int nbins) {
    __shared__ int lh[256];
    lh[threadIdx.x] = 0;
    __syncthreads();
    int ebpb = (E + PB - 1) / PB;
    int e0 = blockIdx.x * ebpb;
    int e1 = min(e0 + ebpb, E);
    for (int e = e0 + threadIdx.x; e < e1; e += 256)
        atomicAdd(&lh[dst[e] >> BINSHIFT], 1);
    __syncthreads();
    bbc[blockIdx.x * 256 + threadIdx.x] = lh[threadIdx.x];
}

// B1: per-bin exclusive scan across the 256 partition blocks.
__global__ __launch_bounds__(256) void binB1_kernel(int* __restrict__ bbc,
                                                    int* __restrict__ binTotal,
                                                    int* __restrict__ binStart) {
    __shared__ int ws[4];
    int b = blockIdx.x;
    int t = threadIdx.x, lane = t & 63, wv = t >> 6;
    int v = bbc[t * 256 + b];
    int sc = v;
#pragma unroll
    for (int d = 1; d < 64; d <<= 1) { int u = __shfl_up(sc, d, 64); if (lane >= d) sc += u; }
    if (lane == 63) ws[wv] = sc;
    __syncthreads();
    int add = 0;
    for (int w = 0; w < wv; w++) add += ws[w];
    bbc[t * 256 + b] = sc - v + add;
    if (t == 255) { int tot = sc + add; binTotal[b] = tot; binStart[b] = tot; }
}

// B2 / generic 1-wave exclusive scan (also used for rowptr chunk sums)
__global__ __launch_bounds__(64) void scan_bsums_kernel(int* __restrict__ bsum, int nchunks) {
    int lane = threadIdx.x;
    int cpl = (nchunks + 63) / 64;     // <= 8 assumed
    int vals[8];
    int i0 = lane * cpl;
    int t = 0;
    for (int k = 0; k < cpl; k++) {
        int i = i0 + k;
        vals[k] = (i < nchunks) ? bsum[i] : 0;
        t += vals[k];
    }
    int sc = t;
#pragma unroll
    for (int d = 1; d < 64; d <<= 1) { int v = __shfl_up(sc, d, 64); if (lane >= d) sc += v; }
    int ex = sc - t;
    for (int k = 0; k < cpl; k++) {
        int i = i0 + k;
        if (i < nchunks) bsum[i] = ex;
        ex += vals[k];
    }
}

// C: partition edges into bin-contiguous packed records. No global atomics.
// record = (doff << 17) | src   (src < 2^17, doff < 2^9)
__global__ __launch_bounds__(256) void binC_kernel(const int* __restrict__ src,
                                                   const int* __restrict__ dst,
                                                   const int* __restrict__ bbc,
                                                   const int* __restrict__ binStart,
                                                   unsigned int* __restrict__ binned,
                                                   int E, int nbins) {
    __shared__ int cur[256];
    int t = threadIdx.x;
    if (t < nbins) cur[t] = binStart[t] + bbc[blockIdx.x * 256 + t];
    __syncthreads();
    int ebpb = (E + PB - 1) / PB;
    int e0 = blockIdx.x * ebpb;
    int e1 = min(e0 + ebpb, E);
    for (int e = e0 + t; e < e1; e += 256) {
        int d = dst[e];
        int b = d >> BINSHIFT;
        int p = atomicAdd(&cur[b], 1);
        binned[p] = ((unsigned int)(d & (BINSZ - 1)) << 17) | (unsigned int)src[e];
    }
}

// H: per-bin node degree histogram (LDS) -> hist + dinv. Replaces global-atomic hist.
__global__ __launch_bounds__(256) void binH_kernel(const unsigned int* __restrict__ binned,
                                                   const int* __restrict__ binStart,
                                                   const int* __restrict__ binTotal,
                                                   int* __restrict__ hist,
                                                   float* __restrict__ dinv, int n) {
    __shared__ int dh[BINSZ];
    int b = blockIdx.x;
    int t = threadIdx.x;
    dh[t] = 0; dh[t + 256] = 0;
    __syncthreads();
    int s0 = binStart[b], cnt = binTotal[b];
    for (int i = t; i < cnt; i += 256)
        atomicAdd(&dh[binned[s0 + i] >> 17], 1);
    __syncthreads();
#pragma unroll
    for (int r = 0; r < 2; r++) {
        int i = t + r * 256;
        int node = (b << BINSHIFT) + i;
        if (node < n) {
            int dg = dh[i];
            hist[node] = dg;
            dinv[node] = 1.0f / sqrtf((float)(dg + 1));
        }
    }
}

// ---------------- rowptr scan over hist (3 phases) ----------------
__global__ __launch_bounds__(256) void scan_sum_kernel(const int* __restrict__ hist,
                                                       int* __restrict__ bsum, int n) {
    __shared__ int wsums[4];
    int lane = threadIdx.x & 63, wv = threadIdx.x >> 6;
    int i0 = blockIdx.x * SCAN_CHUNK + threadIdx.x * 4;
    int t = 0;
#pragma unroll
    for (int k = 0; k < 4; k++) { int i = i0 + k; if (i < n) t += hist[i]; }
#pragma unroll
    for (int d = 32; d > 0; d >>= 1) t += __shfl_down(t, d, 64);
    if (lane == 0) wsums[wv] = t;
    __syncthreads();
    if (threadIdx.x == 0) bsum[blockIdx.x] = wsums[0] + wsums[1] + wsums[2] + wsums[3];
}

__global__ __launch_bounds__(256) void scan_write_kernel(const int* __restrict__ hist,
                                                         const int* __restrict__ bofs,
                                                         int* __restrict__ rowptr,
                                                         int n, int total) {
    __shared__ int wsum[4];
    int lane = threadIdx.x & 63, wv = threadIdx.x >> 6;
    int i0 = blockIdx.x * SCAN_CHUNK + threadIdx.x * 4;
    int h[4]; int t = 0;
#pragma unroll
    for (int k = 0; k < 4; k++) { int i = i0 + k; h[k] = (i < n) ? hist[i] : 0; t += h[k]; }
    int sc = t;
#pragma unroll
    for (int d = 1; d < 64; d <<= 1) { int v = __shfl_up(sc, d, 64); if (lane >= d) sc += v; }
    if (lane == 63) wsum[wv] = sc;
    __syncthreads();
    int wofs = 0;
    for (int w = 0; w < wv; w++) wofs += wsum[w];
    int ex = (sc - t) + wofs + bofs[blockIdx.x];
#pragma unroll
    for (int k = 0; k < 4; k++) { int i = i0 + k; if (i < n) rowptr[i] = ex; ex += h[k]; }
    if (blockIdx.x == 0 && threadIdx.x == 0) rowptr[n] = total;
}

// D: per-bin CSR scatter. LDS countdown + LDS rowptr slice; ssrc writes land in
// a ~32 KB window resident in one XCD's L2 -> writeback ~= payload.
__global__ __launch_bounds__(256) void binD_kernel(const unsigned int* __restrict__ binned,
                                                   const int* __restrict__ binStart,
                                                   const int* __restrict__ binTotal,
                                                   const int* __restrict__ hist,
                                                   const int* __restrict__ rowptr,
                                                   int* __restrict__ ssrc, int n) {
    __shared__ int cntL[BINSZ];
    __shared__ int rpL[BINSZ];
    int b = blockIdx.x;
    int t = threadIdx.x;
#pragma unroll
    for (int r = 0; r < 2; r++) {
        int i = t + r * 256;
        int node = (b << BINSHIFT) + i;
        if (node < n) { cntL[i] = hist[node]; rpL[i] = rowptr[node]; }
    }
    __syncthreads();
    int s0 = binStart[b], cnt = binTotal[b];
    for (int i = t; i < cnt; i += 256) {
        unsigned int rec = binned[s0 + i];
        int doff = rec >> 17;
        int s = rec & 0x1FFFF;
        int idx = atomicSub(&cntL[doff], 1) - 1;
        ssrc[rpL[doff] + idx] = s;
    }
}

// ---------------- dense matmul: T[n, 0..63] = X[n, :K] @ W[K, 64] ----------
template <int K>
__global__ __launch_bounds__(256) void mm_kernel(const float* __restrict__ X,
                                                 const float* __restrict__ W,
                                                 float* __restrict__ T, int nn) {
    const int lane   = threadIdx.x & 63;
    const int wv     = threadIdx.x >> 6;
    const int feat_t = lane & 7;          // 8 feature groups of 8
    const int node_t = lane >> 3;         // 8 node groups of 4 -> 32 nodes/wave
    const int j0 = feat_t * 8;
    const int nb = blockIdx.x * 128 + wv * 32 + node_t * 4;
    if (blockIdx.x * 128 >= nn) return;

    const int nclamp = nn - 1;
    const float* xr0 = X + (size_t)min(nb + 0, nclamp) * K;
    const float* xr1 = X + (size_t)min(nb + 1, nclamp) * K;
    const float* xr2 = X + (size_t)min(nb + 2, nclamp) * K;
    const float* xr3 = X + (size_t)min(nb + 3, nclamp) * K;

    float acc[4][8];
#pragma unroll
    for (int u = 0; u < 4; u++)
#pragma unroll
        for (int v = 0; v < 8; v++) acc[u][v] = 0.f;

#pragma unroll 2
    for (int k = 0; k < K; k += 4) {
        float4 x0 = *(const float4*)(xr0 + k);
        float4 x1 = *(const float4*)(xr1 + k);
        float4 x2 = *(const float4*)(xr2 + k);
        float4 x3 = *(const float4*)(xr3 + k);
#pragma unroll
        for (int kk = 0; kk < 4; kk++) {
            float4 wa = *(const float4*)(W + (size_t)(k + kk) * 64 + j0);
            float4 wb = *(const float4*)(W + (size_t)(k + kk) * 64 + j0 + 4);
            float xs0 = (&x0.x)[kk];
            float xs1 = (&x1.x)[kk];
            float xs2 = (&x2.x)[kk];
            float xs3 = (&x3.x)[kk];
            acc[0][0] += xs0 * wa.x; acc[0][1] += xs0 * wa.y;
            acc[0][2] += xs0 * wa.z; acc[0][3] += xs0 * wa.w;
            acc[0][4] += xs0 * wb.x; acc[0][5] += xs0 * wb.y;
            acc[0][6] += xs0 * wb.z; acc[0][7] += xs0 * wb.w;
            acc[1][0] += xs1 * wa.x; acc[1][1] += xs1 * wa.y;
            acc[1][2] += xs1 * wa.z; acc[1][3] += xs1 * wa.w;
            acc[1][4] += xs1 * wb.x; acc[1][5] += xs1 * wb.y;
            acc[1][6] += xs1 * wb.z; acc[1][7] += xs1 * wb.w;
            acc[2][0] += xs2 * wa.x; acc[2][1] += xs2 * wa.y;
            acc[2][2] += xs2 * wa.z; acc[2][3] += xs2 * wa.w;
            acc[2][4] += xs2 * wb.x; acc[2][5] += xs2 * wb.y;
            acc[2][6] += xs2 * wb.z; acc[2][7] += xs2 * wb.w;
            acc[3][0] += xs3 * wa.x; acc[3][1] += xs3 * wa.y;
            acc[3][2] += xs3 * wa.z; acc[3][3] += xs3 * wa.w;
            acc[3][4] += xs3 * wb.x; acc[3][5] += xs3 * wb.y;
            acc[3][6] += xs3 * wb.z; acc[3][7] += xs3 * wb.w;
        }
    }

#pragma unroll
    for (int u = 0; u < 4; u++) {
        if (nb + u < nn) {
            float* o = T + (size_t)(nb + u) * 64 + j0;
            *(float4*)(o)     = make_float4(acc[u][0], acc[u][1], acc[u][2], acc[u][3]);
            *(float4*)(o + 4) = make_float4(acc[u][4], acc[u][5], acc[u][6], acc[u][7]);
        }
    }
}

// ---------------- pull aggregation + self loop + bias + relu ----------------
__global__ __launch_bounds__(256) void agg_kernel(const float* __restrict__ T,
                                                  const int* __restrict__ rowptr,
                                                  const int* __restrict__ ssrc,
                                                  const float* __restrict__ dinv,
                                                  const float* __restrict__ bias,
                                                  float* __restrict__ O, int nn) {
    int wave = __builtin_amdgcn_readfirstlane((blockIdx.x * 256 + threadIdx.x) >> 6);
    int lane = threadIdx.x & 63;
    if (wave >= nn) return;
    int n = wave;
    float di = dinv[n];
    float acc = di * di * T[(size_t)n * 64 + lane];
    int rb = rowptr[n], re = rowptr[n + 1];
    int i = rb;
    for (; i + 3 < re; i += 4) {
        int s0 = ssrc[i], s1 = ssrc[i + 1], s2 = ssrc[i + 2], s3 = ssrc[i + 3];
        float w0 = di * dinv[s0];
        float w1 = di * dinv[s1];
        float w2 = di * dinv[s2];
        float w3 = di * dinv[s3];
        float v0 = T[(size_t)s0 * 64 + lane];
        float v1 = T[(size_t)s1 * 64 + lane];
        float v2 = T[(size_t)s2 * 64 + lane];
        float v3 = T[(size_t)s3 * 64 + lane];
        acc += w0 * v0;
        acc += w1 * v1;
        acc += w2 * v2;
        acc += w3 * v3;
    }
    for (; i < re; i++) {
        int s0 = ssrc[i];
        acc += di * dinv[s0] * T[(size_t)s0 * 64 + lane];
    }
    float v = acc + bias[lane];
    O[(size_t)n * 64 + lane] = v > 0.f ? v : 0.f;
}

// ---------------- mean pool: exploit sorted batch ids ----------------
__global__ __launch_bounds__(256) void pool_kernel(const float* __restrict__ H,
                                                   const int* __restrict__ batch,
                                                   float* __restrict__ pooled,
                                                   float* __restrict__ gcnt, int nn) {
    int wid = (blockIdx.x * 256 + threadIdx.x) >> 6;
    int lane = threadIdx.x & 63;
    int nwaves = (gridDim.x * 256) >> 6;
    int per = (nn + nwaves - 1) / nwaves;
    int n0 = wid * per;
    int n1 = n0 + per; if (n1 > nn) n1 = nn;
    if (n0 >= n1) return;
    int cur = batch[n0];
    float acc = 0.f, cnt = 0.f;
    for (int n = n0; n < n1; ++n) {
        int g = batch[n];
        if (g != cur) {
            atomicAdd(&pooled[cur * 64 + lane], acc);
            if (lane == 0) atomicAdd(&gcnt[cur], cnt);
            acc = 0.f; cnt = 0.f; cur = g;
        }
        acc += H[(size_t)n * 64 + lane];
        cnt += 1.f;
    }
    atomicAdd(&pooled[cur * 64 + lane], acc);
    if (lane == 0) atomicAdd(&gcnt[cur], cnt);
}

// ---------------- MLP head (single block) ----------------
__global__ __launch_bounds__(256) void head_kernel(const float* __restrict__ pooled,
                                                   const float* __restrict__ gcnt,
                                                   const float* __restrict__ Wm1,
                                                   const float* __restrict__ bm1,
                                                   const float* __restrict__ Wm2,
                                                   const float* __restrict__ bm2,
                                                   float* __restrict__ out) {
    __shared__ float P[NG * 64];
    __shared__ float Z[NG * 64];
    int tid = threadIdx.x;
    for (int i = tid; i < NG * 64; i += 256) {
        int g = i >> 6;
        float c = gcnt[g];
        c = c > 1.f ? c : 1.f;
        P[i] = pooled[i] / c;
    }
    __syncthreads();
    for (int i = tid; i < NG * 64; i += 256) {
        int g = i >> 6, j = i & 63;
        float a = bm1[j];
#pragma unroll 8
        for (int k = 0; k < 64; ++k) a += P[g * 64 + k] * Wm1[k * 64 + j];
        Z[i] = a > 0.f ? a : 0.f;
    }
    __syncthreads();
    for (int i = tid; i < NG * OUTD; i += 256) {
        int g = i / OUTD, o = i % OUTD;
        float a = bm2[o];
#pragma unroll 8
        for (int k = 0; k < 64; ++k) a += Z[g * 64 + k] * Wm2[k * OUTD + o];
        out[i] = a;
    }
}

extern "C" void kernel_launch(void* const* d_in, const int* in_sizes, int n_in,
                              void* d_out, int out_size, void* d_ws, size_t ws_size,
                              hipStream_t stream) {
    const float* x    = (const float*)d_in[0];
    const int*  edge  = (const int*)d_in[1];
    const int*  batch = (const int*)d_in[2];
    const float* W1 = (const float*)d_in[3];
    const float* b1 = (const float*)d_in[4];
    const float* W2 = (const float*)d_in[5];
    const float* b2 = (const float*)d_in[6];
    const float* W3 = (const float*)d_in[7];
    const float* b3 = (const float*)d_in[8];
    const float* Wm1 = (const float*)d_in[9];
    const float* bm1 = (const float*)d_in[10];
    const float* Wm2 = (const float*)d_in[11];
    const float* bm2 = (const float*)d_in[12];

    const int N_ = in_sizes[2];           // 100000 (batch length)
    const int E_ = in_sizes[1] / 2;       // 1600000
    const int* src = edge;
    const int* dst = edge + E_;
    const int nbins = (N_ + BINSZ - 1) >> BINSHIFT;   // 196

    // workspace carve (256 B aligned)
    char* w = (char*)d_ws;
    auto alloc = [&](size_t bytes) -> void* {
        void* p = (void*)w;
        w += (bytes + 255) & ~(size_t)255;
        return p;
    };
    float* dinv   = (float*)alloc((size_t)N_ * 4);
    int*   hist   = (int*)alloc((size_t)N_ * 4);
    int*   rowptr = (int*)alloc((size_t)(N_ + 1) * 4);
    int*   bsum   = (int*)alloc(512 * 4);
    int*   bbc    = (int*)alloc((size_t)256 * 256 * 4);
    int*   binTotal = (int*)alloc(256 * 4);
    int*   binStart = (int*)alloc(256 * 4);
    int*   ssrc   = (int*)alloc((size_t)E_ * 4);
    float* tA     = (float*)alloc((size_t)N_ * 64 * 4);
    float* hB     = (float*)alloc((size_t)N_ * 64 * 4);
    float* pooled = (float*)alloc((size_t)(NG * 64 + NG) * 4);
    float* gcnt   = pooled + NG * 64;
    unsigned int* binned = (unsigned int*)tA;   // alias: consumed before mm writes tA

    const int nchunks = (N_ + SCAN_CHUNK - 1) / SCAN_CHUNK;

    hipMemsetAsync(pooled, 0, (size_t)(NG * 64 + NG) * 4, stream);

    // ---- binned CSR build ----
    binA_kernel<<<PB, 256, 0, stream>>>(dst, bbc, E_, nbins);
    binB1_kernel<<<nbins, 256, 0, stream>>>(bbc, binTotal, binStart);
    scan_bsums_kernel<<<1, 64, 0, stream>>>(binStart, nbins);
    binC_kernel<<<PB, 256, 0, stream>>>(src, dst, bbc, binStart, binned, E_, nbins);
    binH_kernel<<<nbins, 256, 0, stream>>>(binned, binStart, binTotal, hist, dinv, N_);
    scan_sum_kernel<<<nchunks, 256, 0, stream>>>(hist, bsum, N_);
    scan_bsums_kernel<<<1, 64, 0, stream>>>(bsum, nchunks);
    scan_write_kernel<<<nchunks, 256, 0, stream>>>(hist, bsum, rowptr, N_, E_);
    binD_kernel<<<nbins, 256, 0, stream>>>(binned, binStart, binTotal, hist, rowptr, ssrc, N_);

    const int mmblk = (N_ + 127) / 128;           // 128 nodes per block
    const int aggblk = (N_ + 3) / 4;              // 4 waves (nodes) per block

    // layer 1: t = x @ W1 ; h = agg(t) + b1, relu
    mm_kernel<IND><<<mmblk, 256, 0, stream>>>(x, W1, tA, N_);
    agg_kernel<<<aggblk, 256, 0, stream>>>(tA, rowptr, ssrc, dinv, b1, hB, N_);
    // layer 2
    mm_kernel<HD><<<mmblk, 256, 0, stream>>>(hB, W2, tA, N_);
    agg_kernel<<<aggblk, 256, 0, stream>>>(tA, rowptr, ssrc, dinv, b2, hB, N_);
    // layer 3
    mm_kernel<HD><<<mmblk, 256, 0, stream>>>(hB, W3, tA, N_);
    agg_kernel<<<aggblk, 256, 0, stream>>>(tA, rowptr, ssrc, dinv, b3, hB, N_);

    // pool + head
    pool_kernel<<<256, 256, 0, stream>>>(hB, batch, pooled, gcnt, N_);
    head_kernel<<<1, 256, 0, stream>>>(pooled, gcnt, Wm1, bm1, Wm2, bm2, (float*)d_out);
}